// Round 5
// baseline (155.714 us; speedup 1.0000x reference)
//
#include <hip/hip_runtime.h>

// VQ-VAE quantizer, MI355X (gfx950). B=64, C=D=64, H=32, W=32 -> N=65536 tokens, K=1024 codes.
// Round 5: 2 dispatches (finalize folded into vq via last-block-done; ~19us/dispatch measured).
//   vq: 3-product split-bf16 MFMA (hi*hi, hi*lo, lo*hi; lo*lo dropped: ~6e-5 d2 error, <1 flip).
//       Wave tile = 64 tokens x K-quarter: B-frag L2 traffic 537->268 MB (R4 was L2-bound,
//       MfmaUtil 21% == 568TF/2.5PF). Single accumulator chain per group (no a0+a1 add).
//   prep: pack split-bf16 codebook into B-frag order (one 16B store/thread), c2, zero ws.
// Outputs (flat): z_q [4194304] f32 NCHW, loss [1], perplexity [1].

typedef __attribute__((ext_vector_type(8))) short short8;   // 8 bf16 (4 VGPRs)
typedef __attribute__((ext_vector_type(4))) float float4v;  // MFMA C/D frag

#define NELEM 4194304
#define NBLK  1024        // vq grid: 1024 blocks x 64 tokens

// ---- workspace layout (bytes) ----
#define WS_CBF   0        // ushort[131072]: packed split-bf16 codebook, B-frag order (256 KB)
#define WS_C2H   262144   // f32 c2h[1024] = -0.5*||c||^2
#define WS_HIST  266240   // i32 hist[1024]
#define WS_LOSS  270336   // f32 loss_part[64]
#define WS_DONE  270592   // i32 done counter

__device__ __forceinline__ unsigned bf16_rne(float x) {
    unsigned u = __float_as_uint(x);
    return (u + 0x7fffu + ((u >> 16) & 1u)) >> 16;
}

// grid = 68 blocks x 256. Blocks 0..63 pack chunk bx; 64..67 zero hist/loss/done.
// Fragment layout: cbf[((chunk*4 + fid)*64 + lane)*8 + j], fid = split*2 + st,
// lane = kq*16 + col, code = chunk*16 + col, dim d = st*32 + kq*8 + j.
__global__ __launch_bounds__(256) void prep_kernel(
    const float* __restrict__ cb, ushort* __restrict__ cbf,
    float* __restrict__ c2h, int* __restrict__ hist,
    float* __restrict__ loss_part, int* __restrict__ done) {
    __shared__ float s_c2[2][16];
    int tid  = threadIdx.x;
    int lane = tid & 63, wave = tid >> 6;
    int quad = lane >> 4, col = lane & 15;
    int bx   = blockIdx.x;

    if (bx >= 64) {
        hist[(bx - 64) * 256 + tid] = 0;
        if (bx == 64 && tid < 64) loss_part[tid] = 0.f;
        if (bx == 64 && tid == 64) *done = 0;
        return;
    }
    int c = bx, fid = wave;
    int st = fid & 1, split = fid >> 1;
    int code  = c * 16 + col;
    int dbase = st * 32 + quad * 8;
    const float* cp = cb + code * 64 + dbase;
    float4v v0 = *(const float4v*)cp;
    float4v v1 = *(const float4v*)(cp + 4);
    float xs[8] = {v0.x, v0.y, v0.z, v0.w, v1.x, v1.y, v1.z, v1.w};
    short8 frag;
    float ssq = 0.f;
#pragma unroll
    for (int j = 0; j < 8; j++) {
        float x = xs[j];
        ssq = fmaf(x, x, ssq);
        unsigned hb = bf16_rne(x);
        if (split == 0) frag[j] = (short)hb;
        else            frag[j] = (short)bf16_rne(x - __uint_as_float(hb << 16));
    }
    *(short8*)(cbf + ((c * 4 + fid) * 64 + lane) * 8) = frag;   // contiguous 16B store
    if (split == 0) {                    // c2 deterministic reduction (same as R4)
        ssq += __shfl_xor(ssq, 16);
        ssq += __shfl_xor(ssq, 32);
        if (quad == 0) s_c2[st][col] = ssq;
    }
    __syncthreads();
    if (tid < 16) c2h[c * 16 + tid] = -0.5f * (s_c2[0][tid] + s_c2[1][tid]);
}

// grid = 1024 blocks x 256 (4 waves). Block = 64 tokens; each wave: all 64 tokens
// (4 MFMA groups of 16) x its K-quarter (16 chunks of 16 codes). 4-way merge in LDS.
// Last finished block runs the finalize (entropy/perplexity/loss).
__global__ __launch_bounds__(256, 3) void vq_kernel(
    const float* __restrict__ z, const float* __restrict__ cb,
    const ushort* __restrict__ cbf, const float* __restrict__ c2h,
    const int* __restrict__ flg, float* __restrict__ out,
    float* __restrict__ loss_part, int* __restrict__ hist, int* __restrict__ done)
{
    __shared__ float s_q[64 * 65];       // gathered code rows, +1 pad (16.6 KB)
    __shared__ float s_ms[4][64];        // K-quarter merge: score
    __shared__ int   s_mi[4][64];        // K-quarter merge: index
    __shared__ int   s_idx[64];
    __shared__ float s_red[4];
    __shared__ int   s_last;

    int tid  = threadIdx.x;
    int lane = tid & 63, wave = tid >> 6;
    int quad = lane >> 4, col = lane & 15;
    int bx   = blockIdx.x;

    int tokbase = bx * 64;
    int bb = tokbase >> 10, hwb = tokbase & 1023;
    const float* zb = z + bb * 65536 + hwb;

    // ---- A-fragments: 4 groups x {hi,lo} x 2 K-steps, loaded once (64 VGPRs) ----
    short8 ah[4][2], al[4][2];
#pragma unroll
    for (int g = 0; g < 4; g++) {
        int rel = g * 16 + col;                      // token row m = lane&15
#pragma unroll
        for (int st = 0; st < 2; st++) {
            short8 h8, l8;
#pragma unroll
            for (int j = 0; j < 8; j++) {
                int d = st * 32 + quad * 8 + j;      // k = quad*8+j
                float x = zb[d * 1024 + rel];
                unsigned hb = bf16_rne(x);
                h8[j] = (short)hb;
                l8[j] = (short)bf16_rne(x - __uint_as_float(hb << 16));
            }
            ah[g][st] = h8; al[g][st] = l8;
        }
    }

    float best[4][4]; int bidx[4][4];
#pragma unroll
    for (int g = 0; g < 4; g++)
#pragma unroll
        for (int r = 0; r < 4; r++) { best[g][r] = -1e38f; bidx[g][r] = 0; }

    // ---- k-loop: 16 chunks of this wave's K-quarter; no LDS, no barriers ----
    const ushort* cw = cbf + lane * 8;
    for (int cc = 0; cc < 16; cc++) {
        int ch = (wave << 4) + cc;
        const ushort* p = cw + ch * 2048;
        short8 bh0 = *(const short8*)(p + 0);
        short8 bh1 = *(const short8*)(p + 512);
        short8 bl0 = *(const short8*)(p + 1024);
        short8 bl1 = *(const short8*)(p + 1536);
        float  ini = c2h[ch * 16 + col];
        int   code = ch * 16 + col;
#pragma unroll
        for (int g = 0; g < 4; g++) {
            float4v acc = {ini, ini, ini, ini};      // score = dot - c2/2 (argmax)
            acc = __builtin_amdgcn_mfma_f32_16x16x32_bf16(ah[g][0], bh0, acc, 0, 0, 0);
            acc = __builtin_amdgcn_mfma_f32_16x16x32_bf16(ah[g][1], bh1, acc, 0, 0, 0);
            acc = __builtin_amdgcn_mfma_f32_16x16x32_bf16(ah[g][0], bl0, acc, 0, 0, 0);
            acc = __builtin_amdgcn_mfma_f32_16x16x32_bf16(ah[g][1], bl1, acc, 0, 0, 0);
            acc = __builtin_amdgcn_mfma_f32_16x16x32_bf16(al[g][0], bh0, acc, 0, 0, 0);
            acc = __builtin_amdgcn_mfma_f32_16x16x32_bf16(al[g][1], bh1, acc, 0, 0, 0);
#pragma unroll
            for (int r = 0; r < 4; r++) {
                if (acc[r] > best[g][r]) { best[g][r] = acc[r]; bidx[g][r] = code; }
            }
        }
    }

    // ---- cross-lane argmax within each quad (C row = quad*4+r, col = code) ----
#pragma unroll
    for (int g = 0; g < 4; g++) {
#pragma unroll
        for (int r = 0; r < 4; r++) {
            float s = best[g][r]; int ix = bidx[g][r];
#pragma unroll
            for (int m = 1; m <= 8; m <<= 1) {
                float so = __shfl_xor(s, m);
                int   io = __shfl_xor(ix, m);
                if (so > s || (so == s && io < ix)) { s = so; ix = io; }
            }
            if (col == 0) {
                int t = g * 16 + quad * 4 + r;
                s_ms[wave][t] = s; s_mi[wave][t] = ix;
            }
        }
    }
    __syncthreads();

    // ---- merge 4 K-quarters (ascending code order, strict >: first-min ties) ----
    if (tid < 64) {
        float sb = s_ms[0][tid]; int ib = s_mi[0][tid];
#pragma unroll
        for (int q = 1; q < 4; q++) {
            float sq_ = s_ms[q][tid];
            if (sq_ > sb) { sb = sq_; ib = s_mi[q][tid]; }
        }
        s_idx[tid] = ib;
        atomicAdd(&hist[ib], 1);                     // one per token
    }
    __syncthreads();

    // ---- gather selected code rows (wave-uniform row, 256B coalesced) ----
#pragma unroll
    for (int p = 0; p < 16; p++) {
        int i = p * 256 + tid;
        int t = i >> 6, d = i & 63;
        s_q[t * 65 + d] = cb[s_idx[t] * 64 + d];
    }
    __syncthreads();

    // ---- straight-through output + loss (256B contiguous runs per wave) ----
    float ls = 0.f;
#pragma unroll 4
    for (int p = 0; p < 16; p++) {
        int i = p * 256 + tid;
        int d = i >> 6, t = i & 63;
        int a = d * 1024 + t;
        float zv = zb[a];
        float q  = s_q[t * 65 + d];                  // bank(t+d): conflict-free
        float df = q - zv;
        out[bb * 65536 + hwb + a] = zv + df;         // z + (z_q - z)
        ls = fmaf(df, df, ls);
    }
#pragma unroll
    for (int off = 32; off; off >>= 1) ls += __shfl_down(ls, off);
    if (lane == 0) s_red[wave] = ls;
    __syncthreads();
    if (tid == 0) {
        float v = (s_red[0] + s_red[1]) + (s_red[2] + s_red[3]);
        atomicAdd(&loss_part[bx & 63], v);
        __threadfence();                             // release hist/loss before done++
        s_last = (atomicAdd(done, 1) == NBLK - 1);
    }
    __syncthreads();

    // ---- last block finalizes (saves a dispatch ~19us) ----
    if (s_last) {
        float v = 0.f;
#pragma unroll
        for (int i = 0; i < 4; i++) {
            int h = atomicAdd(&hist[tid * 4 + i], 0);          // coherent read
            float e = (float)h * (1.0f / 65536.0f);
            v += e * logf(e + 1e-10f);
        }
#pragma unroll
        for (int off = 32; off; off >>= 1) v += __shfl_down(v, off);
        if (lane == 0) s_red[wave] = v;
        __syncthreads();
        if (tid < 64) {
            float lv = atomicAdd(&loss_part[tid], 0.f);        // coherent read
#pragma unroll
            for (int off = 32; off; off >>= 1) lv += __shfl_down(lv, off);
            if (tid == 0) {
                float ent = (s_red[0] + s_red[1]) + (s_red[2] + s_red[3]);
                out[NELEM + 1] = expf(-ent);                   // perplexity
                float m = lv * (1.0f / (float)NELEM);
                out[NELEM] = (*flg) ? (0.25f * m + m) : 0.0f;  // BETA*mean + mean
            }
        }
    }
}

extern "C" void kernel_launch(void* const* d_in, const int* in_sizes, int n_in,
                              void* d_out, int out_size, void* d_ws, size_t ws_size,
                              hipStream_t stream) {
    const float* z   = (const float*)d_in[0];   // (64,64,32,32) f32 NCHW
    const float* cb  = (const float*)d_in[1];   // (1024,64) f32
    const int*   flg = (const int*)d_in[3];     // flg_train

    float* out = (float*)d_out;
    char*  ws  = (char*)d_ws;

    ushort* cbf       = (ushort*)(ws + WS_CBF);
    float*  c2h       = (float*)(ws + WS_C2H);
    int*    hist      = (int*)(ws + WS_HIST);
    float*  loss_part = (float*)(ws + WS_LOSS);
    int*    done      = (int*)(ws + WS_DONE);

    prep_kernel<<<68, 256, 0, stream>>>(cb, cbf, c2h, hist, loss_part, done);
    vq_kernel<<<NBLK, 256, 0, stream>>>(z, cb, cbf, c2h, flg, out, loss_part, hist, done);
}

// Round 6
// 150.037 us; speedup vs baseline: 1.0378x; 1.0378x over previous
//
#include <hip/hip_runtime.h>

// VQ-VAE quantizer, MI355X (gfx950). B=64, C=D=64, H=32, W=32 -> N=65536 tokens, K=1024 codes.
// Round 6: 4 cheap dispatches (R5 showed dispatch cost ~3us; the ~60us gap is fixed harness
// overhead). Each kernel shaped for its own bottleneck:
//   prep:    pack split-bf16 codebook into B-frag order + c2 + zero ws.       (~2us)
//   argmin:  MFMA-only. R4's register-prefetch k-loop (R5 regressed by removing it:
//            60->97us) + R5's 64-token wave tile (B traffic 268MB) + 3-product distances
//            (bit-identical absmax to 4-product, verified R4 vs R5). Floor ~12.4us
//            (25.8 GFLOP at per-CU MFMA rate 4.85cyc/instr). Writes idx[] + hist.
//   output:  pure streaming: int4 idx, float4 z/out, L2-hot cb gathers, loss. (~7-10us)
//   finalize: entropy -> perplexity, loss.                                    (~2us)
// Outputs (flat): z_q [4194304] f32 NCHW, loss [1], perplexity [1].

typedef __attribute__((ext_vector_type(8))) short short8;   // 8 bf16 (4 VGPRs)
typedef __attribute__((ext_vector_type(4))) float float4v;  // MFMA C/D frag

#define NELEM 4194304

// ---- workspace layout (bytes) ----
#define WS_CBF   0        // ushort[131072]: packed split-bf16 codebook, B-frag order (256 KB)
#define WS_C2H   262144   // f32 c2h[1024] = -0.5*||c||^2
#define WS_HIST  266240   // i32 hist[1024]
#define WS_LOSS  270336   // f32 loss_part[64]
#define WS_IDX   270592   // i32 idx[65536]  (argmin result per token)

__device__ __forceinline__ unsigned bf16_rne(float x) {
    unsigned u = __float_as_uint(x);
    return (u + 0x7fffu + ((u >> 16) & 1u)) >> 16;
}

// grid = 68 blocks x 256. Blocks 0..63 pack chunk bx; 64..67 zero hist; 64 zeroes loss.
// Fragment layout: cbf[((chunk*4 + fid)*64 + lane)*8 + j], fid = split*2 + st,
// lane = kq*16 + col, code = chunk*16 + col, dim d = st*32 + kq*8 + j.
__global__ __launch_bounds__(256) void prep_kernel(
    const float* __restrict__ cb, ushort* __restrict__ cbf,
    float* __restrict__ c2h, int* __restrict__ hist, float* __restrict__ loss_part) {
    __shared__ float s_c2[2][16];
    int tid  = threadIdx.x;
    int lane = tid & 63, wave = tid >> 6;
    int quad = lane >> 4, col = lane & 15;
    int bx   = blockIdx.x;

    if (bx >= 64) {
        hist[(bx - 64) * 256 + tid] = 0;
        if (bx == 64 && tid < 64) loss_part[tid] = 0.f;
        return;
    }
    int c = bx, fid = wave;
    int st = fid & 1, split = fid >> 1;
    int code  = c * 16 + col;
    int dbase = st * 32 + quad * 8;
    const float* cp = cb + code * 64 + dbase;
    float4v v0 = *(const float4v*)cp;
    float4v v1 = *(const float4v*)(cp + 4);
    float xs[8] = {v0.x, v0.y, v0.z, v0.w, v1.x, v1.y, v1.z, v1.w};
    short8 frag;
    float ssq = 0.f;
#pragma unroll
    for (int j = 0; j < 8; j++) {
        float x = xs[j];
        ssq = fmaf(x, x, ssq);
        unsigned hb = bf16_rne(x);
        if (split == 0) frag[j] = (short)hb;
        else            frag[j] = (short)bf16_rne(x - __uint_as_float(hb << 16));
    }
    *(short8*)(cbf + ((c * 4 + fid) * 64 + lane) * 8) = frag;   // contiguous 16B store
    if (split == 0) {                    // c2 deterministic reduction (R4-identical)
        ssq += __shfl_xor(ssq, 16);
        ssq += __shfl_xor(ssq, 32);
        if (quad == 0) s_c2[st][col] = ssq;
    }
    __syncthreads();
    if (tid < 16) c2h[c * 16 + tid] = -0.5f * (s_c2[0][tid] + s_c2[1][tid]);
}

// grid = 1024 blocks x 256 (3 waves/SIMD). Block = 64 tokens; each wave: all 64 tokens
// (4 MFMA groups) x its K-quarter (16 chunks of 16 codes), register-prefetch double buffer.
// 3-product split-bf16 distances (hi*hi + hi*lo + lo*hi; bit-identical to 4-product here).
__global__ __launch_bounds__(256, 3) void argmin_kernel(
    const float* __restrict__ z, const ushort* __restrict__ cbf,
    const float* __restrict__ c2h, int* __restrict__ idx_out, int* __restrict__ hist)
{
    __shared__ float s_ms[4][64];        // K-quarter merge: score
    __shared__ int   s_mi[4][64];        // K-quarter merge: index

    int tid  = threadIdx.x;
    int lane = tid & 63, wave = tid >> 6;
    int quad = lane >> 4, col = lane & 15;
    int bx   = blockIdx.x;

    int tokbase = bx * 64;
    int bb = tokbase >> 10, hwb = tokbase & 1023;
    const float* zb = z + bb * 65536 + hwb;

    // ---- A-fragments: 4 groups x {hi,lo} x 2 K-steps, loaded once (64 VGPRs) ----
    short8 ah[4][2], al[4][2];
#pragma unroll
    for (int g = 0; g < 4; g++) {
        int rel = g * 16 + col;                      // A row m = lane&15 = token
#pragma unroll
        for (int st = 0; st < 2; st++) {
            short8 h8, l8;
#pragma unroll
            for (int j = 0; j < 8; j++) {
                int d = st * 32 + quad * 8 + j;      // k = quad*8+j
                float x = zb[d * 1024 + rel];
                unsigned hb = bf16_rne(x);
                h8[j] = (short)hb;
                l8[j] = (short)bf16_rne(x - __uint_as_float(hb << 16));
            }
            ah[g][st] = h8; al[g][st] = l8;
        }
    }

    float best[4][4]; int bidx[4][4];
#pragma unroll
    for (int g = 0; g < 4; g++)
#pragma unroll
        for (int r = 0; r < 4; r++) { best[g][r] = -1e38f; bidx[g][r] = 0; }

    // ---- k-loop: 16 chunks, register double-buffered prefetch (R4 structure) ----
    int cbase = wave << 4;
    const ushort* cw = cbf + lane * 8;
    {
        const ushort* p0 = cw + cbase * 2048;
        short8 nb0 = *(const short8*)(p0 + 0);
        short8 nb1 = *(const short8*)(p0 + 512);
        short8 nb2 = *(const short8*)(p0 + 1024);
        short8 nb3 = *(const short8*)(p0 + 1536);
        float  nini = c2h[cbase * 16 + col];
        for (int cc = 0; cc < 16; cc++) {
            short8 bh0 = nb0, bh1 = nb1, bl0 = nb2, bl1 = nb3;
            float  ini = nini;
            if (cc < 15) {                            // prefetch next chunk
                const ushort* np = cw + (cbase + cc + 1) * 2048;
                nb0 = *(const short8*)(np + 0);
                nb1 = *(const short8*)(np + 512);
                nb2 = *(const short8*)(np + 1024);
                nb3 = *(const short8*)(np + 1536);
                nini = c2h[(cbase + cc + 1) * 16 + col];
            }
            int code = (cbase + cc) * 16 + col;
#pragma unroll
            for (int g = 0; g < 4; g++) {
                float4v acc = {ini, ini, ini, ini};   // score = dot - c2/2 (argmax)
                acc = __builtin_amdgcn_mfma_f32_16x16x32_bf16(ah[g][0], bh0, acc, 0, 0, 0);
                acc = __builtin_amdgcn_mfma_f32_16x16x32_bf16(ah[g][1], bh1, acc, 0, 0, 0);
                acc = __builtin_amdgcn_mfma_f32_16x16x32_bf16(ah[g][0], bl0, acc, 0, 0, 0);
                acc = __builtin_amdgcn_mfma_f32_16x16x32_bf16(ah[g][1], bl1, acc, 0, 0, 0);
                acc = __builtin_amdgcn_mfma_f32_16x16x32_bf16(al[g][0], bh0, acc, 0, 0, 0);
                acc = __builtin_amdgcn_mfma_f32_16x16x32_bf16(al[g][1], bh1, acc, 0, 0, 0);
#pragma unroll
                for (int r = 0; r < 4; r++) {
                    if (acc[r] > best[g][r]) { best[g][r] = acc[r]; bidx[g][r] = code; }
                }
            }
        }
    }

    // ---- cross-lane argmax within each quad (C row = quad*4+r, C col = code lane) ----
#pragma unroll
    for (int g = 0; g < 4; g++) {
#pragma unroll
        for (int r = 0; r < 4; r++) {
            float s = best[g][r]; int ix = bidx[g][r];
#pragma unroll
            for (int m = 1; m <= 8; m <<= 1) {
                float so = __shfl_xor(s, m);
                int   io = __shfl_xor(ix, m);
                if (so > s || (so == s && io < ix)) { s = so; ix = io; }
            }
            if (col == 0) {
                int t = g * 16 + quad * 4 + r;
                s_ms[wave][t] = s; s_mi[wave][t] = ix;
            }
        }
    }
    __syncthreads();

    // ---- merge 4 K-quarters (ascending code order, strict >: first-min ties) ----
    if (tid < 64) {
        float sb = s_ms[0][tid]; int ib = s_mi[0][tid];
#pragma unroll
        for (int q = 1; q < 4; q++) {
            float sq_ = s_ms[q][tid];
            if (sq_ > sb) { sb = sq_; ib = s_mi[q][tid]; }
        }
        idx_out[tokbase + tid] = ib;
        atomicAdd(&hist[ib], 1);                     // one per token
    }
}

// grid = 4096 blocks x 256: one float4 per thread, fully coalesced; cb gathers L2-hot.
__global__ __launch_bounds__(256) void output_kernel(
    const float* __restrict__ z, const float* __restrict__ cb,
    const int* __restrict__ idx, float* __restrict__ out,
    float* __restrict__ loss_part)
{
    __shared__ float s_red[4];
    int tid = threadIdx.x;
    int i   = blockIdx.x * 256 + tid;        // float4 index
    int e0  = i * 4;                         // NCHW linear elem
    int hw0 = e0 & 1023;
    int t   = e0 >> 10;                      // b*64 + c
    int c   = t & 63, b = t >> 6;

    int4   iv = *(const int4*)(idx + b * 1024 + hw0);   // 4 consecutive tokens
    float4 zv = *(const float4*)(z + e0);
    float q0 = cb[iv.x * 64 + c];
    float q1 = cb[iv.y * 64 + c];
    float q2 = cb[iv.z * 64 + c];
    float q3 = cb[iv.w * 64 + c];
    float d0 = q0 - zv.x, d1 = q1 - zv.y, d2 = q2 - zv.z, d3 = q3 - zv.w;
    float4 ov = {zv.x + d0, zv.y + d1, zv.z + d2, zv.w + d3};   // z + (z_q - z)
    *(float4*)(((float*)out) + e0) = ov;

    float ls = (d0 * d0 + d1 * d1) + (d2 * d2 + d3 * d3);
#pragma unroll
    for (int off = 32; off; off >>= 1) ls += __shfl_down(ls, off);
    if ((tid & 63) == 0) s_red[tid >> 6] = ls;
    __syncthreads();
    if (tid == 0) {
        float v = (s_red[0] + s_red[1]) + (s_red[2] + s_red[3]);
        atomicAdd(&loss_part[blockIdx.x & 63], v);
    }
}

__global__ __launch_bounds__(1024) void finalize_kernel(
    const int* __restrict__ hist, const float* __restrict__ loss_part,
    const int* __restrict__ flg, float* __restrict__ out) {
    __shared__ float red[16];
    int   k = threadIdx.x;
    float e = (float)hist[k] * (1.0f / 65536.0f);
    float v = e * logf(e + 1e-10f);
#pragma unroll
    for (int off = 32; off; off >>= 1) v += __shfl_down(v, off);
    if ((k & 63) == 0) red[k >> 6] = v;
    __syncthreads();
    if (k == 0) {
        float s = 0.f;
#pragma unroll
        for (int i = 0; i < 16; i++) s += red[i];
        out[NELEM + 1] = expf(-s);                     // perplexity

        float ls = 0.f;
        for (int i = 0; i < 64; i++) ls += loss_part[i];
        float m    = ls * (1.0f / (float)NELEM);
        out[NELEM] = (*flg) ? (0.25f * m + m) : 0.0f;  // BETA*mean + mean
    }
}

extern "C" void kernel_launch(void* const* d_in, const int* in_sizes, int n_in,
                              void* d_out, int out_size, void* d_ws, size_t ws_size,
                              hipStream_t stream) {
    const float* z   = (const float*)d_in[0];   // (64,64,32,32) f32 NCHW
    const float* cb  = (const float*)d_in[1];   // (1024,64) f32
    const int*   flg = (const int*)d_in[3];     // flg_train

    float* out = (float*)d_out;
    char*  ws  = (char*)d_ws;

    ushort* cbf       = (ushort*)(ws + WS_CBF);
    float*  c2h       = (float*)(ws + WS_C2H);
    int*    hist      = (int*)(ws + WS_HIST);
    float*  loss_part = (float*)(ws + WS_LOSS);
    int*    idx       = (int*)(ws + WS_IDX);

    prep_kernel<<<68, 256, 0, stream>>>(cb, cbf, c2h, hist, loss_part);
    argmin_kernel<<<1024, 256, 0, stream>>>(z, cbf, c2h, idx, hist);
    output_kernel<<<4096, 256, 0, stream>>>(z, cb, idx, out, loss_part);
    finalize_kernel<<<1, 1024, 0, stream>>>(hist, loss_part, flg, out);
}

// Round 7
// 135.615 us; speedup vs baseline: 1.1482x; 1.1064x over previous
//
#include <hip/hip_runtime.h>

// VQ-VAE quantizer, MI355X (gfx950). B=64, C=D=64, H=32, W=32 -> N=65536 tokens, K=1024 codes.
// Round 7: R6 post-mortem showed argmin was A-frag-prep bound (per-wave ~2.3us VALU convert,
// x4 redundant -> MfmaUtil 19%) and output_kernel was ~35us of scattered cb gathers.
//   prep:   ONE dispatch: split-bf16 z -> A-frag-ready shorts (ONCE per token) into d_out
//           as scratch (argmin reads it before output overwrites) + codebook pack + zero ws.
//   argmin: pure MFMA k-loop (R6 structure: prefetch, 3-product, verified absmax) with
//           A-frags loaded as coalesced dwordx4 (zero conversion VALU).
//   output: LDS row-gather (rows fetched once: 268MB -> 17MB L2 traffic), float4 stream.
//   finalize: entropy -> perplexity, loss.
// Outputs (flat): z_q [4194304] f32 NCHW, loss [1], perplexity [1].

typedef __attribute__((ext_vector_type(8))) short short8;   // 8 bf16 (4 VGPRs)
typedef __attribute__((ext_vector_type(4))) float float4v;  // MFMA C/D frag

#define NELEM 4194304

// ---- workspace layout (bytes) ----
#define WS_CBF   0        // ushort[131072]: packed split-bf16 codebook, B-frag order (256 KB)
#define WS_C2H   262144   // f32 c2h[1024] = -0.5*||c||^2
#define WS_HIST  266240   // i32 hist[1024]
#define WS_LOSS  270336   // f32 loss_part[64]
#define WS_IDX   270592   // i32 idx[65536]
// zs (split-bf16 z, 16,777,216 B) lives in d_out (out_size*4 = 16,777,224 B >= zs) --
// dead space until output_kernel overwrites it after argmin has consumed it.

__device__ __forceinline__ unsigned bf16_rne(float x) {
    unsigned u = __float_as_uint(x);
    return (u + 0x7fffu + ((u >> 16) & 1u)) >> 16;
}

// zs layout (short8 units): id = (((gg*2 + st)*4 + quad)*2 + split)*16 + col
//   gg = global 16-token group (0..4095), st = K-step (dims st*32..+31),
//   quad = lane>>4 (k-quad), split = 0 hi / 1 lo, col = lane&15 (token within group).
// cbf layout (short8 units): id = ((chunk*4 + split*2 + st)*64 + (quad*16 + col))
//   chunk = 16-code chunk, code = chunk*16 + col, dim d = st*32 + quad*8 + j.

// grid = 1092 blocks x 256:
//   0..1023:  zsplit 64 tokens/block (each token converted ONCE)
//   1024..1087: pack codebook chunk (bx-1024) + c2
//   1088..1091: zero hist; 1088 zeroes loss_part
__global__ __launch_bounds__(256) void prep_kernel(
    const float* __restrict__ z, const float* __restrict__ cb,
    ushort* __restrict__ zs, ushort* __restrict__ cbf, float* __restrict__ c2h,
    int* __restrict__ hist, float* __restrict__ loss_part)
{
    __shared__ float s_c2[2][16];
    int tid  = threadIdx.x;
    int lane = tid & 63, wave = tid >> 6;
    int quad = lane >> 4, col = lane & 15;
    int bx   = blockIdx.x;

    if (bx < 1024) {
        int tokbase = bx * 64;
        int bb = tokbase >> 10, hwb = tokbase & 1023;
        const float* zb = z + bb * 65536 + hwb;
        int g  = wave;                 // group within block
        int gg = bx * 4 + g;           // global group
        int rel = g * 16 + col;
#pragma unroll
        for (int st = 0; st < 2; st++) {
            short8 h8, l8;
#pragma unroll
            for (int j = 0; j < 8; j++) {
                int d = st * 32 + quad * 8 + j;
                float x = zb[d * 1024 + rel];
                unsigned hb = bf16_rne(x);
                h8[j] = (short)hb;
                l8[j] = (short)bf16_rne(x - __uint_as_float(hb << 16));
            }
            int base = (((gg * 2 + st) * 4 + quad) * 2 + 0) * 16 + col;
            *(short8*)(zs + base * 8)             = h8;   // split 0
            *(short8*)(zs + (base + 16) * 8)      = l8;   // split 1 (+16 short8)
        }
        return;
    }
    if (bx >= 1088) {
        hist[(bx - 1088) * 256 + tid] = 0;
        if (bx == 1088 && tid < 64) loss_part[tid] = 0.f;
        return;
    }
    // ---- codebook pack (chunk c), R6-identical math ----
    int c = bx - 1024, fid = wave;
    int st = fid & 1, split = fid >> 1;
    int code  = c * 16 + col;
    int dbase = st * 32 + quad * 8;
    const float* cp = cb + code * 64 + dbase;
    float4v v0 = *(const float4v*)cp;
    float4v v1 = *(const float4v*)(cp + 4);
    float xs[8] = {v0.x, v0.y, v0.z, v0.w, v1.x, v1.y, v1.z, v1.w};
    short8 frag;
    float ssq = 0.f;
#pragma unroll
    for (int j = 0; j < 8; j++) {
        float x = xs[j];
        ssq = fmaf(x, x, ssq);
        unsigned hb = bf16_rne(x);
        if (split == 0) frag[j] = (short)hb;
        else            frag[j] = (short)bf16_rne(x - __uint_as_float(hb << 16));
    }
    *(short8*)(cbf + ((c * 4 + fid) * 64 + lane) * 8) = frag;
    if (split == 0) {                    // c2 deterministic reduction (R4/R6-identical)
        ssq += __shfl_xor(ssq, 16);
        ssq += __shfl_xor(ssq, 32);
        if (quad == 0) s_c2[st][col] = ssq;
    }
    __syncthreads();
    if (tid < 16) c2h[c * 16 + tid] = -0.5f * (s_c2[0][tid] + s_c2[1][tid]);
}

// grid = 1024 blocks x 256. Block = 64 tokens; each wave: all 64 tokens (4 groups)
// x its K-quarter (16 chunks), register-prefetch double buffer, 3-product distances.
__global__ __launch_bounds__(256, 3) void argmin_kernel(
    const ushort* __restrict__ zs, const ushort* __restrict__ cbf,
    const float* __restrict__ c2h, int* __restrict__ idx_out, int* __restrict__ hist)
{
    __shared__ float s_ms[4][64];
    __shared__ int   s_mi[4][64];

    int tid  = threadIdx.x;
    int lane = tid & 63, wave = tid >> 6;
    int quad = lane >> 4, col = lane & 15;
    int bx   = blockIdx.x;
    int tokbase = bx * 64;

    // ---- A-fragments: 16 coalesced dwordx4 loads, zero conversion VALU ----
    short8 ah[4][2], al[4][2];
#pragma unroll
    for (int g = 0; g < 4; g++) {
        int gg = bx * 4 + g;
#pragma unroll
        for (int st = 0; st < 2; st++) {
            int base = (((gg * 2 + st) * 4 + quad) * 2 + 0) * 16 + col;
            ah[g][st] = *(const short8*)(zs + base * 8);
            al[g][st] = *(const short8*)(zs + (base + 16) * 8);
        }
    }

    float best[4][4]; int bidx[4][4];
#pragma unroll
    for (int g = 0; g < 4; g++)
#pragma unroll
        for (int r = 0; r < 4; r++) { best[g][r] = -1e38f; bidx[g][r] = 0; }

    // ---- k-loop: 16 chunks, register double-buffered prefetch ----
    int cbase = wave << 4;
    const ushort* cw = cbf + lane * 8;
    {
        const ushort* p0 = cw + cbase * 2048;
        short8 nb0 = *(const short8*)(p0 + 0);
        short8 nb1 = *(const short8*)(p0 + 512);
        short8 nb2 = *(const short8*)(p0 + 1024);
        short8 nb3 = *(const short8*)(p0 + 1536);
        float  nini = c2h[cbase * 16 + col];
        for (int cc = 0; cc < 16; cc++) {
            short8 bh0 = nb0, bh1 = nb1, bl0 = nb2, bl1 = nb3;
            float  ini = nini;
            if (cc < 15) {
                const ushort* np = cw + (cbase + cc + 1) * 2048;
                nb0 = *(const short8*)(np + 0);
                nb1 = *(const short8*)(np + 512);
                nb2 = *(const short8*)(np + 1024);
                nb3 = *(const short8*)(np + 1536);
                nini = c2h[(cbase + cc + 1) * 16 + col];
            }
            int code = (cbase + cc) * 16 + col;
#pragma unroll
            for (int g = 0; g < 4; g++) {
                float4v acc = {ini, ini, ini, ini};   // score = dot - c2/2 (argmax)
                acc = __builtin_amdgcn_mfma_f32_16x16x32_bf16(ah[g][0], bh0, acc, 0, 0, 0);
                acc = __builtin_amdgcn_mfma_f32_16x16x32_bf16(ah[g][1], bh1, acc, 0, 0, 0);
                acc = __builtin_amdgcn_mfma_f32_16x16x32_bf16(ah[g][0], bl0, acc, 0, 0, 0);
                acc = __builtin_amdgcn_mfma_f32_16x16x32_bf16(ah[g][1], bl1, acc, 0, 0, 0);
                acc = __builtin_amdgcn_mfma_f32_16x16x32_bf16(al[g][0], bh0, acc, 0, 0, 0);
                acc = __builtin_amdgcn_mfma_f32_16x16x32_bf16(al[g][1], bh1, acc, 0, 0, 0);
#pragma unroll
                for (int r = 0; r < 4; r++) {
                    if (acc[r] > best[g][r]) { best[g][r] = acc[r]; bidx[g][r] = code; }
                }
            }
        }
    }

    // ---- cross-lane argmax within each quad (C row = quad*4+r, C col = code) ----
#pragma unroll
    for (int g = 0; g < 4; g++) {
#pragma unroll
        for (int r = 0; r < 4; r++) {
            float s = best[g][r]; int ix = bidx[g][r];
#pragma unroll
            for (int m = 1; m <= 8; m <<= 1) {
                float so = __shfl_xor(s, m);
                int   io = __shfl_xor(ix, m);
                if (so > s || (so == s && io < ix)) { s = so; ix = io; }
            }
            if (col == 0) {
                int t = g * 16 + quad * 4 + r;
                s_ms[wave][t] = s; s_mi[wave][t] = ix;
            }
        }
    }
    __syncthreads();

    // ---- merge 4 K-quarters (ascending code order, strict >: first-min ties) ----
    if (tid < 64) {
        float sb = s_ms[0][tid]; int ib = s_mi[0][tid];
#pragma unroll
        for (int q = 1; q < 4; q++) {
            float sq_ = s_ms[q][tid];
            if (sq_ > sb) { sb = sq_; ib = s_mi[q][tid]; }
        }
        idx_out[tokbase + tid] = ib;
        atomicAdd(&hist[ib], 1);
    }
}

// grid = 512 blocks x 256. Block = 128 tokens: gather 128 code rows to LDS ONCE
// (256B coalesced, 17MB total L2 traffic vs R6's 268MB), then float4 stream.
__global__ __launch_bounds__(256) void output_kernel(
    const float* __restrict__ z, const float* __restrict__ cb,
    const int* __restrict__ idx, float* __restrict__ out,
    float* __restrict__ loss_part)
{
    __shared__ int    s_row[128];
    __shared__ float4 s_q4[64 * 33];     // [d][tq] float4 (tokens 4tq..+3), pad 33
    __shared__ float  s_red[4];

    int tid = threadIdx.x, bx = blockIdx.x;
    int tokbase = bx * 128;
    int bb = tokbase >> 10, hwb = tokbase & 1023;

    if (tid < 128) s_row[tid] = idx[tokbase + tid];
    __syncthreads();

    // gather: t wave-uniform, d = lane -> 256B coalesced row reads
#pragma unroll
    for (int p = 0; p < 32; p++) {
        int i = p * 256 + tid;
        int t = i >> 6, d = i & 63;
        float v = cb[s_row[t] * 64 + d];
        ((float*)s_q4)[(d * 33 + (t >> 2)) * 4 + (t & 3)] = v;
    }
    __syncthreads();

    const float* zb = z   + bb * 65536 + hwb;
    float*       ob = out + bb * 65536 + hwb;
    float ls = 0.f;
#pragma unroll
    for (int p = 0; p < 8; p++) {
        int fi = p * 256 + tid;          // 2048 float4s: d = fi>>5, tq = fi&31
        int d = fi >> 5, tq = fi & 31;
        float4 zv = *(const float4*)(zb + d * 1024 + tq * 4);
        float4 qv = s_q4[d * 33 + tq];   // ds_read_b128, stride-16B lanes
        float d0 = qv.x - zv.x, d1 = qv.y - zv.y, d2 = qv.z - zv.z, d3 = qv.w - zv.w;
        float4 ov = {zv.x + d0, zv.y + d1, zv.z + d2, zv.w + d3};   // z + (z_q - z)
        *(float4*)(ob + d * 1024 + tq * 4) = ov;
        ls += (d0 * d0 + d1 * d1) + (d2 * d2 + d3 * d3);
    }
#pragma unroll
    for (int off = 32; off; off >>= 1) ls += __shfl_down(ls, off);
    if ((tid & 63) == 0) s_red[tid >> 6] = ls;
    __syncthreads();
    if (tid == 0) {
        float v = (s_red[0] + s_red[1]) + (s_red[2] + s_red[3]);
        atomicAdd(&loss_part[bx & 63], v);
    }
}

__global__ __launch_bounds__(1024) void finalize_kernel(
    const int* __restrict__ hist, const float* __restrict__ loss_part,
    const int* __restrict__ flg, float* __restrict__ out) {
    __shared__ float red[16];
    int   k = threadIdx.x;
    float e = (float)hist[k] * (1.0f / 65536.0f);
    float v = e * logf(e + 1e-10f);
#pragma unroll
    for (int off = 32; off; off >>= 1) v += __shfl_down(v, off);
    if ((k & 63) == 0) red[k >> 6] = v;
    __syncthreads();
    if (k == 0) {
        float s = 0.f;
#pragma unroll
        for (int i = 0; i < 16; i++) s += red[i];
        out[NELEM + 1] = expf(-s);                     // perplexity

        float ls = 0.f;
        for (int i = 0; i < 64; i++) ls += loss_part[i];
        float m    = ls * (1.0f / (float)NELEM);
        out[NELEM] = (*flg) ? (0.25f * m + m) : 0.0f;  // BETA*mean + mean
    }
}

extern "C" void kernel_launch(void* const* d_in, const int* in_sizes, int n_in,
                              void* d_out, int out_size, void* d_ws, size_t ws_size,
                              hipStream_t stream) {
    const float* z   = (const float*)d_in[0];   // (64,64,32,32) f32 NCHW
    const float* cb  = (const float*)d_in[1];   // (1024,64) f32
    const int*   flg = (const int*)d_in[3];     // flg_train

    float* out = (float*)d_out;
    char*  ws  = (char*)d_ws;

    ushort* cbf       = (ushort*)(ws + WS_CBF);
    float*  c2h       = (float*)(ws + WS_C2H);
    int*    hist      = (int*)(ws + WS_HIST);
    float*  loss_part = (float*)(ws + WS_LOSS);
    int*    idx       = (int*)(ws + WS_IDX);
    ushort* zs        = (ushort*)d_out;          // 16.77 MB scratch inside d_out:
                                                 // consumed by argmin, then overwritten

    prep_kernel<<<1092, 256, 0, stream>>>(z, cb, zs, cbf, c2h, hist, loss_part);
    argmin_kernel<<<1024, 256, 0, stream>>>(zs, cbf, c2h, idx, hist);
    output_kernel<<<512, 256, 0, stream>>>(z, cb, idx, out, loss_part);
    finalize_kernel<<<1, 1024, 0, stream>>>(hist, loss_part, flg, out);
}